// Round 6
// baseline (479.421 us; speedup 1.0000x reference)
//
#include <hip/hip_runtime.h>
#include <math.h>

// ---------------- fast path geometry ----------------
#define SC_BLOCKS 512    // K3 blocks (owns contiguous stripe)
#define SC_THREADS 512   // K3 threads
#define NWAVES (SC_THREADS / 64)
#define BPB 16384        // bins per bucket (power of two)
#define BPB_SHIFT 14
#define NB_PAD 256       // padded array stride (>= nb = 205)
#define NB_MAX 208       // max buckets supported by K3 staging LDS
#define QBITS 18
#define QMASK ((1u << QBITS) - 1u)
#define QSCALE 16384.0f  // 2^14: q = bce * 2^14, bce <= ~9.3 -> q < 2^18
#define CAP 72           // staged keys per bucket (31 residue + tile burst)
#define CAP_PAD 73       // odd LDS stride -> banks spread
#define TILE_F4 512      // float4s per tile (= 2048 elements)
#define NTILE 32         // 512*32 f4 = 16384 f4 = 65536 elements per block
#define CUR_STRIDE 32    // cursor padded to one per 128B line

#define LN2F 0.69314718056f
__device__ __forceinline__ float fast_log(float v) {
  return __builtin_amdgcn_logf(v) * LN2F;  // err ~1e-7 rel << 2^-14 quant
}

__device__ __forceinline__ int bin_of(float xv, float tv, float scale,
                                      int nbin_m1) {
  float g = fabsf(xv - tv);
  int b = (int)(g * scale);  // g >= 0 -> trunc == floor
  return b > nbin_m1 ? nbin_m1 : b;
}

// K1: global bucket counts. LDS hist per block, then one global atomic per
// bucket per block. Full-occupancy grid-stride read of x,t.
__global__ __launch_bounds__(256) void k1_count(
    const float4* __restrict__ x, const float4* __restrict__ t,
    unsigned* __restrict__ colsum, int n4, float scale, int nbin_m1, int nb) {
  __shared__ unsigned cnt[NB_PAD];
  for (int i = threadIdx.x; i < NB_PAD; i += 256) cnt[i] = 0;
  __syncthreads();
  int i = blockIdx.x * blockDim.x + threadIdx.x;
  int stride = gridDim.x * blockDim.x;
  for (; i < n4; i += stride) {
    float4 xv = x[i];
    float4 tv = t[i];
    atomicAdd(&cnt[bin_of(xv.x, tv.x, scale, nbin_m1) >> BPB_SHIFT], 1u);
    atomicAdd(&cnt[bin_of(xv.y, tv.y, scale, nbin_m1) >> BPB_SHIFT], 1u);
    atomicAdd(&cnt[bin_of(xv.z, tv.z, scale, nbin_m1) >> BPB_SHIFT], 1u);
    atomicAdd(&cnt[bin_of(xv.w, tv.w, scale, nbin_m1) >> BPB_SHIFT], 1u);
  }
  __syncthreads();
  for (int b = threadIdx.x; b < nb; b += 256)
    if (cnt[b]) atomicAdd(&colsum[b], cnt[b]);
}

// K2: serial scan -> 32-word-aligned region starts + cursor init + nz=0.
__global__ __launch_bounds__(64) void k2_scan(
    const unsigned* __restrict__ colsum, unsigned* __restrict__ start,
    unsigned* __restrict__ cursor, unsigned* __restrict__ nz, int nb) {
  if (threadIdx.x == 0) {
    unsigned acc = 0;
    for (int b = 0; b < nb; ++b) {
      start[b] = acc;
      cursor[(size_t)b * CUR_STRIDE] = acc;
      acc += (colsum[b] + 31u) & ~31u;  // line-aligned region per bucket
    }
    *nz = 0u;
  }
}

// K3: tiled staged scatter with line-aligned flush + residue carry.
// All main-loop global stores are full aligned 128B lines. Key placement
// within a bucket is nondeterministic, but K4 aggregates order-free.
__global__ __launch_bounds__(SC_THREADS) void k3_scatter(
    const float4* __restrict__ x, const float4* __restrict__ t,
    unsigned* __restrict__ cursor, unsigned* __restrict__ keys, float scale,
    int nbin_m1, int nb) {
  __shared__ unsigned stage[NB_MAX * CAP_PAD];  // 60,736 B
  __shared__ unsigned tcnt[NB_MAX];             // per-tile new count / staged tot
  __shared__ unsigned resv[NB_MAX];             // carried residue (<32)
  __shared__ unsigned posb[NB_MAX];             // reserved flush position
  __shared__ unsigned lcnt[NB_MAX];             // lines to flush
  for (int i = threadIdx.x; i < nb; i += SC_THREADS) resv[i] = 0;
  int base = blockIdx.x * (TILE_F4 * NTILE);
  int wid = threadIdx.x >> 6;
  int lane = threadIdx.x & 63;
  for (int tile = 0; tile < NTILE; ++tile) {
    for (int i = threadIdx.x; i < nb; i += SC_THREADS) tcnt[i] = 0;
    __syncthreads();
    // ---- compute phase: 1 float4 (4 elements) per thread ----
    {
      int f4i = base + tile * TILE_F4 + threadIdx.x;
      float4 xv = x[f4i];
      float4 tv = t[f4i];
      float xs[4] = {xv.x, xv.y, xv.z, xv.w};
      float ts[4] = {tv.x, tv.y, tv.z, tv.w};
#pragma unroll
      for (int k = 0; k < 4; ++k) {
        int b = bin_of(xs[k], ts[k], scale, nbin_m1);
        float bce = -(ts[k] * fast_log(xs[k]) +
                      (1.0f - ts[k]) * fast_log(1.0f - xs[k]));
        unsigned q = (unsigned)(bce * QSCALE + 0.5f);
        if (q > QMASK) q = QMASK;
        unsigned key = ((unsigned)(b & (BPB - 1)) << QBITS) | q;
        int bkt = b >> BPB_SHIFT;
        unsigned r = atomicAdd(&tcnt[bkt], 1u);
        unsigned slot = resv[bkt] + r;
        if (slot < CAP)
          stage[bkt * CAP_PAD + slot] = key;
        else  // rare overflow: exact reserved slot, unaligned single store
          keys[atomicAdd(&cursor[(size_t)bkt * CUR_STRIDE], 1u)] = key;
      }
    }
    __syncthreads();
    // ---- flush A: one thread per bucket reserves whole lines ----
    for (int bkt = threadIdx.x; bkt < nb; bkt += SC_THREADS) {
      unsigned tot = resv[bkt] + tcnt[bkt];
      if (tot > CAP) tot = CAP;  // staged entries actually present
      unsigned lines = tot >> 5;
      lcnt[bkt] = lines;
      tcnt[bkt] = tot;  // reuse as staged-total
      if (lines)
        posb[bkt] = atomicAdd(&cursor[(size_t)bkt * CUR_STRIDE], lines * 32u);
    }
    __syncthreads();
    // ---- flush B: one wave per bucket copies lines, compacts residue ----
    for (int bkt = wid; bkt < nb; bkt += NWAVES) {
      unsigned tot = tcnt[bkt];
      unsigned nfl = lcnt[bkt] * 32u;
      if (nfl) {
        unsigned pos = posb[bkt];
        for (unsigned i = lane; i < nfl; i += 64)
          keys[pos + i] = stage[bkt * CAP_PAD + i];
        unsigned rem = tot - nfl;
        unsigned tmp = 0;
        if ((unsigned)lane < rem) tmp = stage[bkt * CAP_PAD + nfl + lane];
        if ((unsigned)lane < rem) stage[bkt * CAP_PAD + lane] = tmp;
        if (lane == 0) resv[bkt] = rem;
      } else if (lane == 0) {
        resv[bkt] = tot;
      }
    }
    __syncthreads();
  }
  // ---- final flush of residues (partial, unaligned, once per block) ----
  for (int bkt = threadIdx.x; bkt < nb; bkt += SC_THREADS) {
    unsigned rem = resv[bkt];
    if (rem) posb[bkt] = atomicAdd(&cursor[(size_t)bkt * CUR_STRIDE], rem);
  }
  __syncthreads();
  for (int bkt = wid; bkt < nb; bkt += NWAVES) {
    unsigned rem = resv[bkt];
    if (rem && (unsigned)lane < rem)
      keys[posb[bkt] + lane] = stage[bkt * CAP_PAD + lane];
  }
}

// K4: one block per bucket. Packed LDS histogram: u32 = count<<24 | sum_q24.
// Integer accumulation -> order-independent -> deterministic.
__global__ __launch_bounds__(1024) void k4_bucket(
    const unsigned* __restrict__ keys, const unsigned* __restrict__ start,
    const unsigned* __restrict__ colsum, double* __restrict__ S_part,
    unsigned* __restrict__ nz) {
  __shared__ unsigned ph[BPB];  // 64 KB
  for (int i = threadIdx.x; i < BPB; i += 1024) ph[i] = 0u;
  __syncthreads();
  int b = blockIdx.x;
  unsigned s0 = start[b], c = colsum[b];
  for (unsigned i = threadIdx.x; i < c; i += 1024) {
    unsigned k = keys[s0 + i];
    atomicAdd(&ph[k >> QBITS], (1u << 24) | (k & QMASK));
  }
  __syncthreads();
  double S = 0.0;
  unsigned z = 0;
  for (int i = threadIdx.x; i < BPB; i += 1024) {
    unsigned p = ph[i];
    unsigned cc = p >> 24;
    if (cc) {
      z++;
      S += (double)((float)(p & 0xFFFFFFu) * (1.0f / QSCALE) / (float)cc);
    }
  }
  __syncthreads();  // all reads of ph done; reuse for reduction
#pragma unroll
  for (int off = 32; off > 0; off >>= 1) {
    S += __shfl_down(S, off, 64);
    z += __shfl_down(z, off, 64);
  }
  double* dred = (double*)ph;  // ph[0..31]  -> 16 doubles
  unsigned* ired = ph + 32;    // ph[32..47] -> 16 uints
  int wid = threadIdx.x >> 6;
  if ((threadIdx.x & 63) == 0) {
    dred[wid] = S;
    ired[wid] = z;
  }
  __syncthreads();
  if (threadIdx.x == 0) {
    double st = 0.0;
    unsigned zt = 0;
    for (int w = 0; w < 16; ++w) {
      st += dred[w];
      zt += ired[w];
    }
    S_part[b] = st;
    atomicAdd(nz, zt);
  }
}

// K5: out = (sum_b S_b) / nz.
__global__ __launch_bounds__(256) void k5_final(
    const double* __restrict__ S_part, const unsigned* __restrict__ nz,
    float* __restrict__ out, int nb) {
  __shared__ double red[256];
  double s = 0.0;
  for (int i = threadIdx.x; i < nb; i += 256) s += S_part[i];
  red[threadIdx.x] = s;
  __syncthreads();
  for (int off = 128; off > 0; off >>= 1) {
    if (threadIdx.x < off) red[threadIdx.x] += red[threadIdx.x + off];
    __syncthreads();
  }
  if (threadIdx.x == 0) out[0] = (float)(red[0] / (double)(*nz));
}

// ---------------- fallback path (proven round-1 kernels) ----------------
#define FB_BLOCK 256
#define FB_GRID 2048

__global__ __launch_bounds__(FB_BLOCK) void ghm_hist_kernel(
    const float4* __restrict__ x, const float4* __restrict__ t,
    int* __restrict__ hist, int n4, float scale, int nbin_m1) {
  int i = blockIdx.x * blockDim.x + threadIdx.x;
  int stride = gridDim.x * blockDim.x;
  for (; i < n4; i += stride) {
    float4 xv = x[i];
    float4 tv = t[i];
    float gx[4] = {fabsf(xv.x - tv.x), fabsf(xv.y - tv.y),
                   fabsf(xv.z - tv.z), fabsf(xv.w - tv.w)};
#pragma unroll
    for (int k = 0; k < 4; ++k) {
      int b = (int)(gx[k] * scale);
      if (b > nbin_m1) b = nbin_m1;
      atomicAdd(&hist[b], 1);
    }
  }
}

__global__ __launch_bounds__(FB_BLOCK) void ghm_nz_kernel(
    const int* __restrict__ hist, int nbin, int* __restrict__ nz) {
  int i = blockIdx.x * blockDim.x + threadIdx.x;
  int stride = gridDim.x * blockDim.x;
  int c = 0;
  for (; i < nbin; i += stride) c += (hist[i] > 0) ? 1 : 0;
#pragma unroll
  for (int off = 32; off > 0; off >>= 1) c += __shfl_down(c, off, 64);
  if ((threadIdx.x & 63) == 0) atomicAdd(nz, c);
}

__global__ __launch_bounds__(FB_BLOCK) void ghm_loss_kernel(
    const float4* __restrict__ x, const float4* __restrict__ t,
    const int* __restrict__ hist, const int* __restrict__ nz,
    double* __restrict__ partials, int n4, float scale, int nbin_m1,
    float fN) {
  float nzf = (float)(*nz);
  double acc = 0.0;
  int i = blockIdx.x * blockDim.x + threadIdx.x;
  int stride = gridDim.x * blockDim.x;
  for (; i < n4; i += stride) {
    float4 xv = x[i];
    float4 tv = t[i];
    float xs[4] = {xv.x, xv.y, xv.z, xv.w};
    float ts[4] = {tv.x, tv.y, tv.z, tv.w};
    float s = 0.0f;
#pragma unroll
    for (int k = 0; k < 4; ++k) {
      float g = fabsf(xs[k] - ts[k]);
      int b = (int)(g * scale);
      if (b > nbin_m1) b = nbin_m1;
      float cntv = (float)hist[b];
      float gd = fmaxf(cntv * nzf, 1.0f);
      float w = fN / gd;
      float bce = -(ts[k] * logf(xs[k]) + (1.0f - ts[k]) * logf(1.0f - xs[k]));
      s += bce * w;
    }
    acc += (double)s;
  }
  __shared__ double sm[FB_BLOCK];
  sm[threadIdx.x] = acc;
  __syncthreads();
  for (int off = FB_BLOCK / 2; off > 0; off >>= 1) {
    if (threadIdx.x < off) sm[threadIdx.x] += sm[threadIdx.x + off];
    __syncthreads();
  }
  if (threadIdx.x == 0) partials[blockIdx.x] = sm[0];
}

__global__ __launch_bounds__(FB_BLOCK) void ghm_final_kernel(
    const double* __restrict__ partials, float* __restrict__ out, int nparts,
    double invN) {
  __shared__ double sm[FB_BLOCK];
  double a = 0.0;
  for (int i = threadIdx.x; i < nparts; i += FB_BLOCK) a += partials[i];
  sm[threadIdx.x] = a;
  __syncthreads();
  for (int off = FB_BLOCK / 2; off > 0; off >>= 1) {
    if (threadIdx.x < off) sm[threadIdx.x] += sm[threadIdx.x + off];
    __syncthreads();
  }
  if (threadIdx.x == 0) out[0] = (float)(sm[0] * invN);
}

extern "C" void kernel_launch(void* const* d_in, const int* in_sizes, int n_in,
                              void* d_out, int out_size, void* d_ws,
                              size_t ws_size, hipStream_t stream) {
  const float* x = (const float*)d_in[0];
  const float* t = (const float*)d_in[1];
  float* out = (float*)d_out;

  long long N = (long long)in_sizes[0];          // 33554432
  int nbin = (int)(N / 10);                      // 3355443
  float scale = (float)((double)nbin - 0.0001);  // == f32(nbin) here
  int n4 = (int)(N / 4);
  int nb = (nbin + BPB - 1) / BPB;  // 205 buckets

  // fast-path workspace layout
  size_t off_colsum = 0;
  size_t off_start = off_colsum + NB_PAD * 4;
  size_t off_cursor = off_start + NB_PAD * 4;
  size_t off_nz = off_cursor + (size_t)NB_PAD * CUR_STRIDE * 4;
  size_t off_Spart = off_nz + 256;
  size_t off_keys = (off_Spart + NB_PAD * 8 + 255) & ~(size_t)255;
  // regions: per-bucket aligned up to 32 words
  size_t needed = off_keys + ((size_t)N + (size_t)nb * 32) * 4;

  bool fast = (ws_size >= needed) && (N % 4 == 0) &&
              (n4 == SC_BLOCKS * TILE_F4 * NTILE) && (nb <= NB_MAX);

  if (fast) {
    unsigned* colsum = (unsigned*)((char*)d_ws + off_colsum);
    unsigned* start = (unsigned*)((char*)d_ws + off_start);
    unsigned* cursor = (unsigned*)((char*)d_ws + off_cursor);
    unsigned* nz = (unsigned*)((char*)d_ws + off_nz);
    double* S_part = (double*)((char*)d_ws + off_Spart);
    unsigned* keys = (unsigned*)((char*)d_ws + off_keys);

    hipMemsetAsync(colsum, 0, NB_PAD * 4, stream);
    k1_count<<<2048, 256, 0, stream>>>((const float4*)x, (const float4*)t,
                                       colsum, n4, scale, nbin - 1, nb);
    k2_scan<<<1, 64, 0, stream>>>(colsum, start, cursor, nz, nb);
    k3_scatter<<<SC_BLOCKS, SC_THREADS, 0, stream>>>(
        (const float4*)x, (const float4*)t, cursor, keys, scale, nbin - 1,
        nb);
    k4_bucket<<<nb, 1024, 0, stream>>>(keys, start, colsum, S_part, nz);
    k5_final<<<1, 256, 0, stream>>>(S_part, nz, out, nb);
  } else {
    // round-1 proven path
    int* hist = (int*)d_ws;
    size_t hist_bytes = (size_t)nbin * 4;
    int* nzi = (int*)((char*)d_ws + hist_bytes);
    size_t part_off = (hist_bytes + 4 + 7) & ~(size_t)7;
    double* partials = (double*)((char*)d_ws + part_off);

    hipMemsetAsync(d_ws, 0, part_off, stream);
    ghm_hist_kernel<<<FB_GRID, FB_BLOCK, 0, stream>>>(
        (const float4*)x, (const float4*)t, hist, n4, scale, nbin - 1);
    ghm_nz_kernel<<<FB_GRID, FB_BLOCK, 0, stream>>>(hist, nbin, (int*)nzi);
    ghm_loss_kernel<<<FB_GRID, FB_BLOCK, 0, stream>>>(
        (const float4*)x, (const float4*)t, hist, (const int*)nzi, partials,
        n4, scale, nbin - 1, (float)N);
    ghm_final_kernel<<<1, FB_BLOCK, 0, stream>>>(partials, out, FB_GRID,
                                                 1.0 / (double)N);
  }
}